// Round 1
// baseline (211.642 us; speedup 1.0000x reference)
//
#include <hip/hip_runtime.h>
#include <math.h>

// Problem constants (fixed by the reference).
constexpr int B_ROWS = 32768;
constexpr int C_COLS = 1000;
constexpr int VEC4   = C_COLS / 4;   // 250 float4 per row; row base = 4000 B -> 16B aligned

// One wave (64 lanes) per row. Each lane owns up to 4 float4 (16 elements):
//   group 0: elements 4*lane      .. 4*lane+3
//   group 1: elements 4*lane+256  .. (+3)
//   group 2: elements 4*lane+512  .. (+3)
//   group 3: elements 4*lane+768  .. (+3)   (only lanes < 58: 192+lane < 250)
__global__ __launch_bounds__(256) void ols_loss_kernel(
    const float* __restrict__ output,   // [B, C]
    const int*   __restrict__ target,   // [B]
    const float* __restrict__ lams,     // [C, C]
    float*       __restrict__ d_loss,   // scalar
    float*       __restrict__ lams_upd, // [C, C]
    float*       __restrict__ cnt_upd)  // [C]
{
    __shared__ float s_loss[4];         // 256 threads -> 4 waves
    const int lane = threadIdx.x & 63;
    const int wid  = threadIdx.x >> 6;
    const int wavesPerBlock = blockDim.x >> 6;
    const int gwave = blockIdx.x * wavesPerBlock + wid;
    const int nwave = gridDim.x * wavesPerBlock;
    const bool has3 = (lane + 192) < VEC4;   // lane < 58

    float lossAcc = 0.0f;

    for (int row = gwave; row < B_ROWS; row += nwave) {
        const float4* xr = reinterpret_cast<const float4*>(output + (size_t)row * C_COLS);
        float4 v0 = xr[lane];
        float4 v1 = xr[lane + 64];
        float4 v2 = xr[lane + 128];
        float4 v3 = has3 ? xr[lane + 192]
                         : make_float4(-INFINITY, -INFINITY, -INFINITY, -INFINITY);

        // ---- per-lane max + first-occurrence argmax (indices strictly increasing) ----
        float m  = v0.x;
        int   am = 4 * lane;
#define OLS_UPD(val, idx) { float _v = (val); if (_v > m) { m = _v; am = (idx); } }
        OLS_UPD(v0.y, 4*lane + 1)  OLS_UPD(v0.z, 4*lane + 2)  OLS_UPD(v0.w, 4*lane + 3)
        OLS_UPD(v1.x, 4*lane + 256) OLS_UPD(v1.y, 4*lane + 257)
        OLS_UPD(v1.z, 4*lane + 258) OLS_UPD(v1.w, 4*lane + 259)
        OLS_UPD(v2.x, 4*lane + 512) OLS_UPD(v2.y, 4*lane + 513)
        OLS_UPD(v2.z, 4*lane + 514) OLS_UPD(v2.w, 4*lane + 515)
        OLS_UPD(v3.x, 4*lane + 768) OLS_UPD(v3.y, 4*lane + 769)
        OLS_UPD(v3.z, 4*lane + 770) OLS_UPD(v3.w, 4*lane + 771)
#undef OLS_UPD

        // ---- wave reduce (max, argmin-index tie-break => first occurrence) ----
#pragma unroll
        for (int off = 32; off > 0; off >>= 1) {
            float om = __shfl_xor(m, off);
            int   oa = __shfl_xor(am, off);
            if (om > m || (om == m && oa < am)) { m = om; am = oa; }
        }

        // ---- sum of exp(x - max); -INF fillers contribute exp(-inf)=0 ----
        float s =
            __expf(v0.x - m) + __expf(v0.y - m) + __expf(v0.z - m) + __expf(v0.w - m) +
            __expf(v1.x - m) + __expf(v1.y - m) + __expf(v1.z - m) + __expf(v1.w - m) +
            __expf(v2.x - m) + __expf(v2.y - m) + __expf(v2.z - m) + __expf(v2.w - m) +
            __expf(v3.x - m) + __expf(v3.y - m) + __expf(v3.z - m) + __expf(v3.w - m);
#pragma unroll
        for (int off = 32; off > 0; off >>= 1) s += __shfl_xor(s, off);

        const float lse = m + __logf(s);

        const int   t   = target[row];                               // wave-uniform
        const float x_t = output[(size_t)row * C_COLS + t];          // wave-uniform

        // ---- soft-CE: dot(lams[t], x) and rowsum(lams[t]) ----
        const float4* lr = reinterpret_cast<const float4*>(lams + (size_t)t * C_COLS);
        float4 l0 = lr[lane];
        float4 l1 = lr[lane + 64];
        float4 l2 = lr[lane + 128];
        float dot = l0.x*v0.x + l0.y*v0.y + l0.z*v0.z + l0.w*v0.w
                  + l1.x*v1.x + l1.y*v1.y + l1.z*v1.z + l1.w*v1.w
                  + l2.x*v2.x + l2.y*v2.y + l2.z*v2.z + l2.w*v2.w;
        float rs  = l0.x + l0.y + l0.z + l0.w
                  + l1.x + l1.y + l1.z + l1.w
                  + l2.x + l2.y + l2.z + l2.w;
        if (has3) {
            float4 l3 = lr[lane + 192];
            dot += l3.x*v3.x + l3.y*v3.y + l3.z*v3.z + l3.w*v3.w;
            rs  += l3.x + l3.y + l3.z + l3.w;
        }
#pragma unroll
        for (int off = 32; off > 0; off >>= 1) {
            dot += __shfl_xor(dot, off);
            rs  += __shfl_xor(rs,  off);
        }

        // per-row loss contribution:
        //   0.5*(lse - x_t)           [hard CE, -log_prob at target]
        // + 0.5*(lse*rowsum - dot)    [soft CE, -sum(lams[t]*(x - lse))]
        if (lane == 0) lossAcc += 0.5f * ((lse - x_t) + (lse * rs - dot));

        // ---- update_loss_lams: only when prediction correct (~B/C rows) ----
        if (am == t) {
            const float inv = 1.0f / s;
            float* dst = lams_upd + (size_t)t * C_COLS;
            atomicAdd(&dst[4*lane + 0],   __expf(v0.x - m) * inv);
            atomicAdd(&dst[4*lane + 1],   __expf(v0.y - m) * inv);
            atomicAdd(&dst[4*lane + 2],   __expf(v0.z - m) * inv);
            atomicAdd(&dst[4*lane + 3],   __expf(v0.w - m) * inv);
            atomicAdd(&dst[4*lane + 256], __expf(v1.x - m) * inv);
            atomicAdd(&dst[4*lane + 257], __expf(v1.y - m) * inv);
            atomicAdd(&dst[4*lane + 258], __expf(v1.z - m) * inv);
            atomicAdd(&dst[4*lane + 259], __expf(v1.w - m) * inv);
            atomicAdd(&dst[4*lane + 512], __expf(v2.x - m) * inv);
            atomicAdd(&dst[4*lane + 513], __expf(v2.y - m) * inv);
            atomicAdd(&dst[4*lane + 514], __expf(v2.z - m) * inv);
            atomicAdd(&dst[4*lane + 515], __expf(v2.w - m) * inv);
            if (has3) {
                atomicAdd(&dst[4*lane + 768], __expf(v3.x - m) * inv);
                atomicAdd(&dst[4*lane + 769], __expf(v3.y - m) * inv);
                atomicAdd(&dst[4*lane + 770], __expf(v3.z - m) * inv);
                atomicAdd(&dst[4*lane + 771], __expf(v3.w - m) * inv);
            }
            if (lane == 0) atomicAdd(&cnt_upd[t], 1.0f);
        }
    }

    // ---- block-level loss reduction -> one atomic per block ----
    if (lane == 0) s_loss[wid] = lossAcc;
    __syncthreads();
    if (threadIdx.x == 0) {
        float tot = 0.0f;
        for (int i = 0; i < wavesPerBlock; ++i) tot += s_loss[i];
        atomicAdd(d_loss, tot * (1.0f / (float)B_ROWS));
    }
}

extern "C" void kernel_launch(void* const* d_in, const int* in_sizes, int n_in,
                              void* d_out, int out_size, void* d_ws, size_t ws_size,
                              hipStream_t stream) {
    const float* output = (const float*)d_in[0];   // [B, C] f32
    const int*   target = (const int*)d_in[1];     // [B] int
    const float* lams   = (const float*)d_in[2];   // [C, C] f32

    float* out      = (float*)d_out;
    float* d_loss   = out;                          // [1]
    float* lams_upd = out + 1;                      // [C, C]
    float* cnt_upd  = out + 1 + C_COLS * C_COLS;    // [C]

    // d_out is poisoned 0xAA before every timed launch; outputs are accumulated
    // via atomics, so zero-init first (async memset is graph-capture safe).
    hipMemsetAsync(d_out, 0, (size_t)out_size * sizeof(float), stream);

    dim3 grid(2048), block(256);
    ols_loss_kernel<<<grid, block, 0, stream>>>(output, target, lams,
                                                d_loss, lams_upd, cnt_upd);
}